// Round 3
// baseline (1903.841 us; speedup 1.0000x reference)
//
#include <hip/hip_runtime.h>

#define DEVINL __device__ __forceinline__

typedef __attribute__((ext_vector_type(8))) __bf16 bf16x8;
typedef __attribute__((ext_vector_type(4))) float f32x4;
typedef __attribute__((ext_vector_type(8))) unsigned short u16x8;

DEVINL unsigned short f2bf(float x) {
  unsigned u = __builtin_bit_cast(unsigned, x);
  u += 0x7FFFu + ((u >> 16) & 1u);
  return (unsigned short)(u >> 16);
}

#define BARRIER() asm volatile("s_barrier" ::: "memory")

template <int N>
DEVINL void waitvm() {
  asm volatile("s_waitcnt vmcnt(%0)" ::"n"(N) : "memory");
}

DEVINL void gload16(const void* g, void* l) {
  __builtin_amdgcn_global_load_lds(
      (const __attribute__((address_space(1))) void*)g,
      (__attribute__((address_space(3))) void*)l, 16, 0, 0);
}

// ---------------- prep: downsample mean + residual (bf16) ----------------
__global__ __launch_bounds__(256) void prep_kernel(
    const float* __restrict__ F, unsigned short* __restrict__ RES,
    float* __restrict__ DS, int n) {
  const int t = threadIdx.x;
  const int row = blockIdx.x * 16 + (t >> 4);
  const int cg = t & 15;
  if (row >= n) return;
  const float4* f4 = (const float4*)(F + (size_t)row * 128 + cg * 8);
  float4 v0 = f4[0], v1 = f4[1];
  float v[8] = {v0.x, v0.y, v0.z, v0.w, v1.x, v1.y, v1.z, v1.w};
  float s[8] = {v0.x, v0.y, v0.z, v0.w, v1.x, v1.y, v1.z, v1.w};
#pragma unroll
  for (int i = 0; i < 8; ++i) s[i] += __shfl_xor(s[i], 4);
#pragma unroll
  for (int i = 0; i < 8; ++i) s[i] += __shfl_xor(s[i], 8);
  u16x8 rb;
#pragma unroll
  for (int i = 0; i < 8; ++i) rb[i] = f2bf(v[i] - 0.25f * s[i]);
  *(u16x8*)(RES + (size_t)row * 128 + cg * 8) = rb;
  if (cg < 4) {
    float4 d0 = {0.25f * s[0], 0.25f * s[1], 0.25f * s[2], 0.25f * s[3]};
    float4 d1 = {0.25f * s[4], 0.25f * s[5], 0.25f * s[6], 0.25f * s[7]};
    float4* dp = (float4*)(DS + (size_t)row * 32 + cg * 8);
    dp[0] = d0;
    dp[1] = d1;
  }
}

// ---------------- weight pack: B-fragment layout, bf16 ----------------
template <int CIN, int COUT>
DEVINL void pack_one(const float* __restrict__ W, unsigned short* __restrict__ P, int g) {
  const int n = g % COUT;
  const int t = g / COUT;
  const int q = t & 3;
  const int t2 = t >> 2;
  const int ks = t2 % (CIN / 32);
  const int k = t2 / (CIN / 32);
  const float* src = W + ((size_t)k * CIN + ks * 32 + q * 8) * COUT + n;
  unsigned short* dst = P + (size_t)g * 8;
#pragma unroll
  for (int j = 0; j < 8; ++j) dst[j] = f2bf(src[(size_t)j * COUT]);
}

__global__ __launch_bounds__(256) void pack_kernel(
    const float* __restrict__ W0, const float* __restrict__ W1,
    const float* __restrict__ W2, unsigned short* __restrict__ P0,
    unsigned short* __restrict__ P1, unsigned short* __restrict__ P2) {
  int g = blockIdx.x * 256 + threadIdx.x;
  if (g < 55296)
    pack_one<128, 128>(W0, P0, g);
  else if (g < 69120)
    pack_one<128, 32>(W1, P1, g - 55296);
  else if (g < 72576)
    pack_one<32, 32>(W2, P2, g - 69120);
}

// ---------------- zero row N of the gather sources ----------------
__global__ void zero_tail(unsigned short* a, unsigned short* b, unsigned short* c) {
  int t = threadIdx.x;
  if (t < 128) { a[t] = 0; b[t] = 0; }
  if (t < 32) c[t] = 0;
}

// ---------------- SPARSE conv v3 (CIN=128): wave-independent tiles ----------------
// Each of 8 waves owns whole 32x128 tiles (t = wave, t += 8) with ZERO barriers
// in the main loop:
//   A: gathered DIRECTLY to VGPRs (frag = contiguous 16B row slice), 1 tile deep.
//   B: register frags from L2 (0.88MB, L2-hot), pipelined 2 ks-steps deep.
//   scatter: ds_add_f32 atomics into padded f32 LDS accumulator (fire-and-forget,
//            race-safe across concurrently-scattering waves).
// klist rows/dests are ds_read well before use. Compiler-tracked vmcnt only.
template <int COUT, int MINW>
__global__ __launch_bounds__(512, MINW) void spconv_sp(
    const unsigned short* __restrict__ X, const unsigned short* __restrict__ Bp,
    const int* __restrict__ nbr, unsigned short* __restrict__ Y, int nr) {
  constexpr int CIN = 128;
  constexpr int KS = 4;
  constexpr int BM = 192;
  constexpr int MT = 32;
  constexpr int NF = COUT / 16;
  constexpr int ACCW = COUT + 4;  // 132 (or 36): stride%32=4 spreads scatter banks
  constexpr int MAXT = 27 * 6 + 4;

  __shared__ float accS[(BM + 1) * ACCW];  // +1 dummy row for pad entries
  __shared__ int klist[MAXT * MT];
  __shared__ int tileKs[MAXT + 1];
  __shared__ int wsum[8];

  const int tid = threadIdx.x;
  const int lane = tid & 63;
  const int wave = tid >> 6;
  const int q = lane >> 4;
  const int l16 = lane & 15;
  const int base = blockIdx.x * BM;

  // ---- zero accumulator ----
  for (int i = tid; i < (BM + 1) * ACCW; i += 512) accS[i] = 0.f;

  // ---- build compacted tile lists (27 ballots, prologue only) ----
  const bool rowOk = (tid < BM) && (base + tid < nr);
  int nt = 0;
  int vNext = nr;
  if (rowOk) vNext = nbr[base + tid];
#pragma unroll 1
  for (int k = 0; k < 27; ++k) {
    int v = vNext;
    if (k + 1 < 27) {
      vNext = nr;
      if (rowOk) vNext = nbr[(size_t)(k + 1) * nr + base + tid];
    }
    bool valid = rowOk && (v != nr);
    unsigned long long b = __ballot(valid);
    if (lane == 0) wsum[wave] = __popcll(b);
    int lanePre = __popcll(b & ((1ull << lane) - 1));
    __syncthreads();
    int pre = lanePre, cnt = 0;
#pragma unroll
    for (int w = 0; w < 3; ++w) {
      int c = wsum[w];
      if (w < wave) pre += c;
      cnt += c;
    }
    if (cnt) {
      int tiles = (cnt + MT - 1) >> 5;
      if (valid) klist[nt * MT + pre] = v | (tid << 19);
      int pad = tiles * MT - cnt;
      if (tid < pad) klist[nt * MT + cnt + tid] = nr | (BM << 19);
      if (tid < tiles) tileKs[nt + tid] = k;
      nt += tiles;
    }
    __syncthreads();
  }
  const int NT = nt;
  const int NTm1 = NT - 1;

  // ---- per-lane bases ----
  const unsigned short* xq = X + q * 8;
  const unsigned short* bbL = Bp + ((size_t)q * COUT + l16) * 8;

  auto bload = [&](int k, int ks, int j) {
    return *(const bf16x8*)(bbL + (((size_t)(k * KS + ks) * 4) * COUT + j * 16) * 8);
  };

  bf16x8 aA[2][KS], aB[2][KS], bf0[NF], bf1[NF];
  f32x4 acc[2][NF];

  // ---- prime ----
  const int t0 = wave;
  int gn0 = klist[t0 * MT + l16] & 0x7FFFF;
  int gn1 = klist[t0 * MT + 16 + l16] & 0x7FFFF;
#pragma unroll
  for (int ks = 0; ks < KS; ++ks) {
    aA[0][ks] = *(const bf16x8*)(xq + (size_t)gn0 * CIN + ks * 32);
    aA[1][ks] = *(const bf16x8*)(xq + (size_t)gn1 * CIN + ks * 32);
  }
  int kCur = tileKs[t0];
#pragma unroll
  for (int j = 0; j < NF; ++j) bf0[j] = bload(kCur, 0, j);
#pragma unroll
  for (int j = 0; j < NF; ++j) bf1[j] = bload(kCur, 1, j);
  {
    int tn = (t0 + 8 <= NTm1) ? t0 + 8 : NTm1;
    gn0 = klist[tn * MT + l16] & 0x7FFFF;
    gn1 = klist[tn * MT + 16 + l16] & 0x7FFFF;
  }

  auto body = [&](int t, bf16x8(&aC)[2][KS], bf16x8(&aN)[2][KS]) {
    const int tnext = (t + 8 <= NTm1) ? t + 8 : NTm1;
    const int kNext = tileKs[tnext];
    const int4 d0 = *(const int4*)&klist[t * MT + q * 4];
    const int4 d1 = *(const int4*)&klist[t * MT + 16 + q * 4];
    const f32x4 z = {0.f, 0.f, 0.f, 0.f};
    // ---- ks=0 (acc init from literal zero) ----
#pragma unroll
    for (int j = 0; j < NF; ++j)
      acc[0][j] = __builtin_amdgcn_mfma_f32_16x16x32_bf16(aC[0][0], bf0[j], z, 0, 0, 0);
#pragma unroll
    for (int j = 0; j < NF; ++j)
      acc[1][j] = __builtin_amdgcn_mfma_f32_16x16x32_bf16(aC[1][0], bf0[j], z, 0, 0, 0);
#pragma unroll
    for (int j = 0; j < NF; ++j) bf0[j] = bload(kCur, 2, j);  // B(ks=2) in flight
    // A prefetch for next tile (uses gn read last iteration)
#pragma unroll
    for (int ks = 0; ks < KS; ++ks) {
      aN[0][ks] = *(const bf16x8*)(xq + (size_t)gn0 * CIN + ks * 32);
      aN[1][ks] = *(const bf16x8*)(xq + (size_t)gn1 * CIN + ks * 32);
    }
    // ---- ks=1 ----
#pragma unroll
    for (int j = 0; j < NF; ++j)
      acc[0][j] = __builtin_amdgcn_mfma_f32_16x16x32_bf16(aC[0][1], bf1[j], acc[0][j], 0, 0, 0);
#pragma unroll
    for (int j = 0; j < NF; ++j)
      acc[1][j] = __builtin_amdgcn_mfma_f32_16x16x32_bf16(aC[1][1], bf1[j], acc[1][j], 0, 0, 0);
#pragma unroll
    for (int j = 0; j < NF; ++j) bf1[j] = bload(kCur, 3, j);  // B(ks=3) in flight
    // klist rows for the tile after next
    {
      int tn2 = (t + 16 <= NTm1) ? t + 16 : NTm1;
      gn0 = klist[tn2 * MT + l16] & 0x7FFFF;
      gn1 = klist[tn2 * MT + 16 + l16] & 0x7FFFF;
    }
    // ---- ks=2 ----
#pragma unroll
    for (int j = 0; j < NF; ++j)
      acc[0][j] = __builtin_amdgcn_mfma_f32_16x16x32_bf16(aC[0][2], bf0[j], acc[0][j], 0, 0, 0);
#pragma unroll
    for (int j = 0; j < NF; ++j)
      acc[1][j] = __builtin_amdgcn_mfma_f32_16x16x32_bf16(aC[1][2], bf0[j], acc[1][j], 0, 0, 0);
#pragma unroll
    for (int j = 0; j < NF; ++j) bf0[j] = bload(kNext, 0, j);  // next tile's B(0)
    // ---- ks=3 ----
#pragma unroll
    for (int j = 0; j < NF; ++j)
      acc[0][j] = __builtin_amdgcn_mfma_f32_16x16x32_bf16(aC[0][3], bf1[j], acc[0][j], 0, 0, 0);
#pragma unroll
    for (int j = 0; j < NF; ++j)
      acc[1][j] = __builtin_amdgcn_mfma_f32_16x16x32_bf16(aC[1][3], bf1[j], acc[1][j], 0, 0, 0);
#pragma unroll
    for (int j = 0; j < NF; ++j) bf1[j] = bload(kNext, 1, j);  // next tile's B(1)
    kCur = kNext;
    // ---- scatter: ds_add_f32 atomics (no return, no ordering needed) ----
    const int dr0[4] = {d0.x >> 19, d0.y >> 19, d0.z >> 19, d0.w >> 19};
    const int dr1[4] = {d1.x >> 19, d1.y >> 19, d1.z >> 19, d1.w >> 19};
#pragma unroll
    for (int rr = 0; rr < 4; ++rr)
#pragma unroll
      for (int j = 0; j < NF; ++j) {
        atomicAdd(&accS[dr0[rr] * ACCW + j * 16 + l16], acc[0][j][rr]);
        atomicAdd(&accS[dr1[rr] * ACCW + j * 16 + l16], acc[1][j][rr]);
      }
  };

  // ---- barrier-free main loop: 2x unrolled for static A ping-pong ----
#pragma unroll 1
  for (int t = t0; t < NT; t += 16) {
    body(t, aA, aB);
    if (t + 8 < NT) body(t + 8, aB, aA);
  }

  // ---- epilogue: f32 accumulator -> bf16 rows ----
  __syncthreads();
  constexpr int CH = COUT / 8;
  for (int s = tid; s < BM * CH; s += 512) {
    int rrow = s / CH, c8 = (s % CH) * 8;
    int row = base + rrow;
    if (row < nr) {
      const float* ap = &accS[rrow * ACCW + c8];
      u16x8 ob;
#pragma unroll
      for (int i = 0; i < 8; ++i) ob[i] = f2bf(ap[i]);
      *(u16x8*)(Y + (size_t)row * COUT + c8) = ob;
    }
  }
}

// ---------------- dense gather-GEMM sparse conv (conv2) ----------------
template <int CIN, int COUT, int WM, int WN, bool FINAL, int MINB>
__global__ __launch_bounds__(256, MINB) void spconv(
    const unsigned short* __restrict__ X, const unsigned short* __restrict__ Bp,
    const int* __restrict__ nbr, unsigned short* __restrict__ Y,
    float* __restrict__ OUT, const float* __restrict__ DS, int nr) {
  constexpr int BM = 128;
  constexpr int KS = CIN / 32;
  constexpr int WROWS = BM / WM;
  constexpr int WCOLS = COUT / WN;
  constexpr int MF = WROWS / 16;
  constexpr int NF = WCOLS / 16;
  constexpr int CPR = CIN / 8;
  constexpr int SWZ = (CPR < 8 ? CPR - 1 : 7);
  constexpr int ROWB = CIN * 2;
  constexpr int ACH = BM * CPR;
  constexpr int APF = ACH / 256;
  constexpr int NB = KS * NF;

  __shared__ unsigned short As[2][BM * CIN];
  __shared__ int IdxS[27 * BM];

  const int tid = threadIdx.x;
  const int lane = tid & 63;
  const int wave = tid >> 6;
  const int wm = wave / WN;
  const int wn = wave % WN;
  const int base = blockIdx.x * BM;
  const int q = lane >> 4;
  const int l16 = lane & 15;

  for (int f = tid; f < 27 * BM; f += 256) {
    int nn = base + (f & (BM - 1));
    IdxS[f] = (nn < nr) ? nbr[(size_t)(f >> 7) * nr + nn] : nr;
  }
  __syncthreads();

  const unsigned short* bbase = Bp + ((size_t)q * COUT + wn * WCOLS + l16) * 8;

  bf16x8 bA[NB], bB[NB];

  auto loadB = [&](bf16x8(&dst)[NB], int k) {
#pragma unroll
    for (int ks = 0; ks < KS; ++ks)
#pragma unroll
      for (int j = 0; j < NF; ++j)
        dst[ks * NF + j] = *(const bf16x8*)(
            bbase + ((size_t)k * CIN * COUT) + ((size_t)(ks * 4) * COUT + j * 16) * 8);
  };

  auto issueA = [&](int k) {
    const int kb = k & 1;
#pragma unroll
    for (int pp = 0; pp < APF; ++pp) {
      int slot = pp * 256 + tid;
      int r = slot / CPR;
      int cc = (slot % CPR) * 16;
      int c = (cc ^ ((r & SWZ) << 4)) >> 4;
      int g = IdxS[k * BM + r];
      gload16(X + (size_t)g * CIN + c * 8, (char*)(&As[kb][0]) + slot * 16);
    }
  };

  f32x4 acc[MF][NF] = {};

  auto mfmaStep = [&](int kb, const bf16x8(&bf)[NB]) {
    const char* Ab = (const char*)(&As[kb][0]);
#pragma unroll
    for (int ks = 0; ks < KS; ++ks) {
      bf16x8 af[MF];
#pragma unroll
      for (int i = 0; i < MF; ++i) {
        int r = wm * WROWS + i * 16 + l16;
        int db = r * ROWB + (((ks * 64 + q * 16) & (ROWB - 1)) ^ ((r & SWZ) << 4));
        af[i] = __builtin_bit_cast(bf16x8, *(const uint4*)(Ab + db));
      }
#pragma unroll
      for (int i = 0; i < MF; ++i)
#pragma unroll
        for (int j = 0; j < NF; ++j)
          acc[i][j] = __builtin_amdgcn_mfma_f32_16x16x32_bf16(af[i], bf[ks * NF + j],
                                                              acc[i][j], 0, 0, 0);
    }
  };

  loadB(bA, 0);
  issueA(0);

#pragma unroll 1
  for (int k = 0; k < 26; k += 2) {
    loadB(bB, k + 1);
    issueA(k + 1);
    waitvm<NB + APF>();
    BARRIER();
    mfmaStep(0, bA);
    BARRIER();
    if (k + 2 < 27) {
      loadB(bA, k + 2);
      issueA(k + 2);
      waitvm<NB + APF>();
    } else {
      waitvm<0>();
    }
    BARRIER();
    mfmaStep(1, bB);
    BARRIER();
  }
  waitvm<0>();
  BARRIER();
  mfmaStep(0, bA);

#pragma unroll
  for (int i = 0; i < MF; ++i)
#pragma unroll
    for (int j = 0; j < NF; ++j)
#pragma unroll
      for (int r = 0; r < 4; ++r) {
        int row = base + wm * WROWS + i * 16 + q * 4 + r;
        int col = wn * WCOLS + j * 16 + l16;
        if (row < nr) {
          float v = acc[i][j][r];
          if constexpr (FINAL)
            OUT[(size_t)row * COUT + col] = v + DS[(size_t)row * COUT + col];
          else
            Y[(size_t)row * COUT + col] = f2bf(v);
        }
      }
}

// ---------------- launch ----------------
extern "C" void kernel_launch(void* const* d_in, const int* in_sizes, int n_in,
                              void* d_out, int out_size, void* d_ws, size_t ws_size,
                              hipStream_t stream) {
  const float* feats = (const float*)d_in[0];
  const float* W0 = (const float*)d_in[1];
  const float* W1 = (const float*)d_in[2];
  const float* W2 = (const float*)d_in[3];
  const int* nbr = (const int*)d_in[4];
  const int n = in_sizes[0] / 128;
  float* out = (float*)d_out;

  char* p = (char*)d_ws;
  auto take = [&](size_t bytes) {
    char* r = p;
    p += (bytes + 255) & ~(size_t)255;
    return r;
  };
  unsigned short* resB = (unsigned short*)take((size_t)(n + 1) * 128 * 2);
  unsigned short* y0 = (unsigned short*)take((size_t)(n + 1) * 128 * 2);
  unsigned short* y1 = (unsigned short*)take((size_t)(n + 1) * 32 * 2);
  float* ds = (float*)take((size_t)n * 32 * 4);
  unsigned short* p0 = (unsigned short*)take((size_t)27 * 128 * 128 * 2);
  unsigned short* p1 = (unsigned short*)take((size_t)27 * 128 * 32 * 2);
  unsigned short* p2 = (unsigned short*)take((size_t)27 * 32 * 32 * 2);

  prep_kernel<<<(n + 15) / 16, 256, 0, stream>>>(feats, resB, ds, n);
  pack_kernel<<<284, 256, 0, stream>>>(W0, W1, W2, p0, p1, p2);
  zero_tail<<<1, 128, 0, stream>>>(resB + (size_t)n * 128, y0 + (size_t)n * 128,
                                   y1 + (size_t)n * 32);
  const int gbs = (n + 191) / 192;
  // conv0: 128->128 sparse v3 (wave-independent tiles, barrier-free)
  spconv_sp<128, 2><<<gbs, 512, 0, stream>>>(resB, p0, nbr, y0, n);
  // conv1: 128->32 sparse v3 (small accumulator -> 2 blocks/CU)
  spconv_sp<32, 4><<<gbs, 512, 0, stream>>>(y0, p1, nbr, y1, n);
  // conv2: 32->32 dense path (known-good). KS=1, NB=2, small LDS -> 4+ blocks/CU.
  const int gb = (n + 127) / 128;
  spconv<32, 32, 4, 1, true, 4>
      <<<gb, 256, 0, stream>>>(y1, p2, nbr, nullptr, out, ds, n);
}

// Round 4
// 738.499 us; speedup vs baseline: 2.5780x; 2.5780x over previous
//
#include <hip/hip_runtime.h>

#define DEVINL __device__ __forceinline__

typedef __attribute__((ext_vector_type(8))) __bf16 bf16x8;
typedef __attribute__((ext_vector_type(4))) float f32x4;
typedef __attribute__((ext_vector_type(8))) unsigned short u16x8;

DEVINL unsigned short f2bf(float x) {
  unsigned u = __builtin_bit_cast(unsigned, x);
  u += 0x7FFFu + ((u >> 16) & 1u);
  return (unsigned short)(u >> 16);
}

#define BARRIER() asm volatile("s_barrier" ::: "memory")

template <int N>
DEVINL void waitvm() {
  asm volatile("s_waitcnt vmcnt(%0)" ::"n"(N) : "memory");
}

DEVINL void gload16(const void* g, void* l) {
  __builtin_amdgcn_global_load_lds(
      (const __attribute__((address_space(1))) void*)g,
      (__attribute__((address_space(3))) void*)l, 16, 0, 0);
}

// ---------------- prep: downsample mean + residual (bf16) ----------------
__global__ __launch_bounds__(256) void prep_kernel(
    const float* __restrict__ F, unsigned short* __restrict__ RES,
    float* __restrict__ DS, int n) {
  const int t = threadIdx.x;
  const int row = blockIdx.x * 16 + (t >> 4);
  const int cg = t & 15;
  if (row >= n) return;
  const float4* f4 = (const float4*)(F + (size_t)row * 128 + cg * 8);
  float4 v0 = f4[0], v1 = f4[1];
  float v[8] = {v0.x, v0.y, v0.z, v0.w, v1.x, v1.y, v1.z, v1.w};
  float s[8] = {v0.x, v0.y, v0.z, v0.w, v1.x, v1.y, v1.z, v1.w};
#pragma unroll
  for (int i = 0; i < 8; ++i) s[i] += __shfl_xor(s[i], 4);
#pragma unroll
  for (int i = 0; i < 8; ++i) s[i] += __shfl_xor(s[i], 8);
  u16x8 rb;
#pragma unroll
  for (int i = 0; i < 8; ++i) rb[i] = f2bf(v[i] - 0.25f * s[i]);
  *(u16x8*)(RES + (size_t)row * 128 + cg * 8) = rb;
  if (cg < 4) {
    float4 d0 = {0.25f * s[0], 0.25f * s[1], 0.25f * s[2], 0.25f * s[3]};
    float4 d1 = {0.25f * s[4], 0.25f * s[5], 0.25f * s[6], 0.25f * s[7]};
    float4* dp = (float4*)(DS + (size_t)row * 32 + cg * 8);
    dp[0] = d0;
    dp[1] = d1;
  }
}

// ---------------- weight pack: B-fragment layout, bf16 ----------------
template <int CIN, int COUT>
DEVINL void pack_one(const float* __restrict__ W, unsigned short* __restrict__ P, int g) {
  const int n = g % COUT;
  const int t = g / COUT;
  const int q = t & 3;
  const int t2 = t >> 2;
  const int ks = t2 % (CIN / 32);
  const int k = t2 / (CIN / 32);
  const float* src = W + ((size_t)k * CIN + ks * 32 + q * 8) * COUT + n;
  unsigned short* dst = P + (size_t)g * 8;
#pragma unroll
  for (int j = 0; j < 8; ++j) dst[j] = f2bf(src[(size_t)j * COUT]);
}

__global__ __launch_bounds__(256) void pack_kernel(
    const float* __restrict__ W0, const float* __restrict__ W1,
    const float* __restrict__ W2, unsigned short* __restrict__ P0,
    unsigned short* __restrict__ P1, unsigned short* __restrict__ P2) {
  int g = blockIdx.x * 256 + threadIdx.x;
  if (g < 55296)
    pack_one<128, 128>(W0, P0, g);
  else if (g < 69120)
    pack_one<128, 32>(W1, P1, g - 55296);
  else if (g < 72576)
    pack_one<32, 32>(W2, P2, g - 69120);
}

// ---------------- zero row N of the gather sources ----------------
__global__ void zero_tail(unsigned short* a, unsigned short* b, unsigned short* c) {
  int t = threadIdx.x;
  if (t < 128) { a[t] = 0; b[t] = 0; }
  if (t < 32) c[t] = 0;
}

// ---------------- gather-GEMM sparse conv ----------------
// A: double-buffered direct-to-LDS (global_load_lds, pre-swizzled source).
// B: per-wave column slice in REGISTERS, prefetched one k ahead from global
//    (L2-hot, shared across all blocks), ping-ponged between two named
//    fragment arrays (compile-time indices only — no scratch).
// Per pair of k: {loadB(k+1); issueA(k+1); vmcnt(NB+APF); barrier; MFMA(k);
//                 barrier; ...}  — prefetches stay in flight across barriers.
template <int CIN, int COUT, int WM, int WN, bool FINAL, int MINB>
__global__ __launch_bounds__(256, MINB) void spconv(
    const unsigned short* __restrict__ X, const unsigned short* __restrict__ Bp,
    const int* __restrict__ nbr, unsigned short* __restrict__ Y,
    float* __restrict__ OUT, const float* __restrict__ DS, int nr) {
  constexpr int BM = 128;
  constexpr int KS = CIN / 32;
  constexpr int WROWS = BM / WM;
  constexpr int WCOLS = COUT / WN;
  constexpr int MF = WROWS / 16;
  constexpr int NF = WCOLS / 16;
  constexpr int CPR = CIN / 8;                  // 16B chunks per A row
  constexpr int SWZ = (CPR < 8 ? CPR - 1 : 7);
  constexpr int ROWB = CIN * 2;                 // bytes per A row
  constexpr int ACH = BM * CPR;
  constexpr int APF = ACH / 256;                // A issues per thread per k
  constexpr int NB = KS * NF;                   // B frag loads per lane per k

  __shared__ unsigned short As[2][BM * CIN];
  __shared__ int IdxS[27 * BM];

  const int tid = threadIdx.x;
  const int lane = tid & 63;
  const int wave = tid >> 6;
  const int wm = wave / WN;
  const int wn = wave % WN;
  const int base = blockIdx.x * BM;
  const int q = lane >> 4;
  const int l16 = lane & 15;

  // ---- stage all 27*BM neighbor indices once ----
  for (int f = tid; f < 27 * BM; f += 256) {
    int nn = base + (f & (BM - 1));
    IdxS[f] = (nn < nr) ? nbr[(size_t)(f >> 7) * nr + nn] : nr;
  }
  __syncthreads();  // clean vmcnt baseline before the pipeline

  // per-lane B base: frag(k,ks,j) at bbase + (k*CIN + ks*4*... )
  const unsigned short* bbase = Bp + ((size_t)q * COUT + wn * WCOLS + l16) * 8;

  bf16x8 bA[NB], bB[NB];

  auto loadB = [&](bf16x8(&dst)[NB], int k) {
#pragma unroll
    for (int ks = 0; ks < KS; ++ks)
#pragma unroll
      for (int j = 0; j < NF; ++j)
        dst[ks * NF + j] = *(const bf16x8*)(
            bbase + ((size_t)k * CIN * COUT) + ((size_t)(ks * 4) * COUT + j * 16) * 8);
  };

  auto issueA = [&](int k) {
    const int kb = k & 1;
#pragma unroll
    for (int pp = 0; pp < APF; ++pp) {
      int slot = pp * 256 + tid;
      int r = slot / CPR;
      int cc = (slot % CPR) * 16;
      int c = (cc ^ ((r & SWZ) << 4)) >> 4;  // pre-swizzled source chunk
      int g = IdxS[k * BM + r];
      gload16(X + (size_t)g * CIN + c * 8, (char*)(&As[kb][0]) + slot * 16);
    }
  };

  f32x4 acc[MF][NF] = {};

  auto mfmaStep = [&](int kb, const bf16x8(&bf)[NB]) {
    const char* Ab = (const char*)(&As[kb][0]);
#pragma unroll
    for (int ks = 0; ks < KS; ++ks) {
      bf16x8 af[MF];
#pragma unroll
      for (int i = 0; i < MF; ++i) {
        int r = wm * WROWS + i * 16 + l16;
        int db = r * ROWB + (((ks * 64 + q * 16) & (ROWB - 1)) ^ ((r & SWZ) << 4));
        af[i] = __builtin_bit_cast(bf16x8, *(const uint4*)(Ab + db));
      }
#pragma unroll
      for (int i = 0; i < MF; ++i)
#pragma unroll
        for (int j = 0; j < NF; ++j)
          acc[i][j] = __builtin_amdgcn_mfma_f32_16x16x32_bf16(af[i], bf[ks * NF + j],
                                                              acc[i][j], 0, 0, 0);
    }
  };

  loadB(bA, 0);
  issueA(0);

#pragma unroll 1
  for (int k = 0; k < 26; k += 2) {
    // ---- even half: compute k from bA/As[0], prefetch k+1 ----
    loadB(bB, k + 1);
    issueA(k + 1);
    waitvm<NB + APF>();  // A(k) + B(k) landed; k+1 stays in flight
    BARRIER();
    mfmaStep(0, bA);
    BARRIER();
    // ---- odd half: compute k+1 from bB/As[1], prefetch k+2 ----
    if (k + 2 < 27) {
      loadB(bA, k + 2);
      issueA(k + 2);
      waitvm<NB + APF>();
    } else {
      waitvm<0>();
    }
    BARRIER();
    mfmaStep(1, bB);
    BARRIER();
  }
  // ---- tail k=26 (bA/As[0] loaded in last odd half) ----
  waitvm<0>();
  BARRIER();
  mfmaStep(0, bA);

  // ---- epilogue: C layout col=lane&15, row=(lane>>4)*4+reg ----
#pragma unroll
  for (int i = 0; i < MF; ++i)
#pragma unroll
    for (int j = 0; j < NF; ++j)
#pragma unroll
      for (int r = 0; r < 4; ++r) {
        int row = base + wm * WROWS + i * 16 + q * 4 + r;
        int col = wn * WCOLS + j * 16 + l16;
        if (row < nr) {
          float v = acc[i][j][r];
          if constexpr (FINAL)
            OUT[(size_t)row * COUT + col] = v + DS[(size_t)row * COUT + col];
          else
            Y[(size_t)row * COUT + col] = f2bf(v);
        }
      }
}

// ---------------- launch ----------------
extern "C" void kernel_launch(void* const* d_in, const int* in_sizes, int n_in,
                              void* d_out, int out_size, void* d_ws, size_t ws_size,
                              hipStream_t stream) {
  const float* feats = (const float*)d_in[0];
  const float* W0 = (const float*)d_in[1];
  const float* W1 = (const float*)d_in[2];
  const float* W2 = (const float*)d_in[3];
  const int* nbr = (const int*)d_in[4];
  const int n = in_sizes[0] / 128;
  float* out = (float*)d_out;

  char* p = (char*)d_ws;
  auto take = [&](size_t bytes) {
    char* r = p;
    p += (bytes + 255) & ~(size_t)255;
    return r;
  };
  unsigned short* resB = (unsigned short*)take((size_t)(n + 1) * 128 * 2);
  unsigned short* y0 = (unsigned short*)take((size_t)(n + 1) * 128 * 2);
  unsigned short* y1 = (unsigned short*)take((size_t)(n + 1) * 32 * 2);
  float* ds = (float*)take((size_t)n * 32 * 4);
  unsigned short* p0 = (unsigned short*)take((size_t)27 * 128 * 128 * 2);
  unsigned short* p1 = (unsigned short*)take((size_t)27 * 128 * 32 * 2);
  unsigned short* p2 = (unsigned short*)take((size_t)27 * 32 * 32 * 2);

  prep_kernel<<<(n + 15) / 16, 256, 0, stream>>>(feats, resB, ds, n);
  pack_kernel<<<284, 256, 0, stream>>>(W0, W1, W2, p0, p1, p2);
  zero_tail<<<1, 128, 0, stream>>>(resB + (size_t)n * 128, y0 + (size_t)n * 128,
                                   y1 + (size_t)n * 32);
  const int gb = (n + 127) / 128;
  // conv0: 128->128.  WM=2,WN=2 -> per-wave 64x64, A-LDS redundancy x2 (was x4).
  spconv<128, 128, 2, 2, false, 2>
      <<<gb, 256, 0, stream>>>(resB, p0, nbr, y0, nullptr, nullptr, n);
  // conv1: 128->32.  WM=4,WN=1 -> NF=2, NB=8.
  spconv<128, 32, 4, 1, false, 2>
      <<<gb, 256, 0, stream>>>(y0, p1, nbr, y1, nullptr, nullptr, n);
  // conv2: 32->32.  KS=1, NB=2, small LDS -> 4+ blocks/CU.
  spconv<32, 32, 4, 1, true, 4>
      <<<gb, 256, 0, stream>>>(y1, p2, nbr, nullptr, out, ds, n);
}

// Round 5
// 518.980 us; speedup vs baseline: 3.6684x; 1.4230x over previous
//
#include <hip/hip_runtime.h>

#define DEVINL __device__ __forceinline__

typedef __attribute__((ext_vector_type(8))) __bf16 bf16x8;
typedef __attribute__((ext_vector_type(4))) float f32x4;
typedef __attribute__((ext_vector_type(8))) unsigned short u16x8;

DEVINL unsigned short f2bf(float x) {
  unsigned u = __builtin_bit_cast(unsigned, x);
  u += 0x7FFFu + ((u >> 16) & 1u);
  return (unsigned short)(u >> 16);
}

#define BARRIER() asm volatile("s_barrier" ::: "memory")

template <int N>
DEVINL void waitvm() {
  asm volatile("s_waitcnt vmcnt(%0)" ::"n"(N) : "memory");
}

DEVINL void gload16(const void* g, void* l) {
  __builtin_amdgcn_global_load_lds(
      (const __attribute__((address_space(1))) void*)g,
      (__attribute__((address_space(3))) void*)l, 16, 0, 0);
}

// ---------------- prep: downsample mean + residual (bf16) ----------------
__global__ __launch_bounds__(256) void prep_kernel(
    const float* __restrict__ F, unsigned short* __restrict__ RES,
    float* __restrict__ DS, int n) {
  const int t = threadIdx.x;
  const int row = blockIdx.x * 16 + (t >> 4);
  const int cg = t & 15;
  if (row >= n) return;
  const float4* f4 = (const float4*)(F + (size_t)row * 128 + cg * 8);
  float4 v0 = f4[0], v1 = f4[1];
  float v[8] = {v0.x, v0.y, v0.z, v0.w, v1.x, v1.y, v1.z, v1.w};
  float s[8] = {v0.x, v0.y, v0.z, v0.w, v1.x, v1.y, v1.z, v1.w};
#pragma unroll
  for (int i = 0; i < 8; ++i) s[i] += __shfl_xor(s[i], 4);
#pragma unroll
  for (int i = 0; i < 8; ++i) s[i] += __shfl_xor(s[i], 8);
  u16x8 rb;
#pragma unroll
  for (int i = 0; i < 8; ++i) rb[i] = f2bf(v[i] - 0.25f * s[i]);
  *(u16x8*)(RES + (size_t)row * 128 + cg * 8) = rb;
  if (cg < 4) {
    float4 d0 = {0.25f * s[0], 0.25f * s[1], 0.25f * s[2], 0.25f * s[3]};
    float4 d1 = {0.25f * s[4], 0.25f * s[5], 0.25f * s[6], 0.25f * s[7]};
    float4* dp = (float4*)(DS + (size_t)row * 32 + cg * 8);
    dp[0] = d0;
    dp[1] = d1;
  }
}

// ---------------- weight pack: B-fragment layout, bf16 ----------------
template <int CIN, int COUT>
DEVINL void pack_one(const float* __restrict__ W, unsigned short* __restrict__ P, int g) {
  const int n = g % COUT;
  const int t = g / COUT;
  const int q = t & 3;
  const int t2 = t >> 2;
  const int ks = t2 % (CIN / 32);
  const int k = t2 / (CIN / 32);
  const float* src = W + ((size_t)k * CIN + ks * 32 + q * 8) * COUT + n;
  unsigned short* dst = P + (size_t)g * 8;
#pragma unroll
  for (int j = 0; j < 8; ++j) dst[j] = f2bf(src[(size_t)j * COUT]);
}

__global__ __launch_bounds__(256) void pack_kernel(
    const float* __restrict__ W0, const float* __restrict__ W1,
    const float* __restrict__ W2, unsigned short* __restrict__ P0,
    unsigned short* __restrict__ P1, unsigned short* __restrict__ P2) {
  int g = blockIdx.x * 256 + threadIdx.x;
  if (g < 55296)
    pack_one<128, 128>(W0, P0, g);
  else if (g < 69120)
    pack_one<128, 32>(W1, P1, g - 55296);
  else if (g < 72576)
    pack_one<32, 32>(W2, P2, g - 69120);
}

// ---------------- zero row N of the gather sources ----------------
__global__ void zero_tail(unsigned short* a, unsigned short* b, unsigned short* c) {
  int t = threadIdx.x;
  if (t < 128) { a[t] = 0; b[t] = 0; }
  if (t < 32) c[t] = 0;
}

// ---------------- gather-GEMM sparse conv ----------------
// Round-0 proven structure with one change: staging granularity BK (<= CIN).
// BK=64 halves the A-LDS buffers (2x16KB) so LDS = 46.6KB -> 3 blocks/CU
// (was 2), raising waves/SIMD 2->3 for latency hiding. K-loop becomes
// 27*(CIN/BK) half-steps with the identical prefetch / counted-vmcnt /
// 2-barrier discipline. Per-output accumulation order unchanged (ks order
// preserved) -> bit-identical results.
template <int CIN, int COUT, int BK, int WM, int WN, bool FINAL, int MINB>
__global__ __launch_bounds__(256, MINB) void spconv(
    const unsigned short* __restrict__ X, const unsigned short* __restrict__ Bp,
    const int* __restrict__ nbr, unsigned short* __restrict__ Y,
    float* __restrict__ OUT, const float* __restrict__ DS, int nr) {
  constexpr int BM = 128;
  constexpr int H = CIN / BK;      // staging steps per k
  constexpr int S = 27 * H;        // total pipeline steps
  constexpr int KSL = BK / 32;     // local 32-k slices per step
  constexpr int WROWS = BM / WM;
  constexpr int WCOLS = COUT / WN;
  constexpr int MF = WROWS / 16;
  constexpr int NF = WCOLS / 16;
  constexpr int CPR = BK / 8;                   // 16B chunks per A row (per step)
  constexpr int SWZ = (CPR < 8 ? CPR - 1 : 7);
  constexpr int RB = BK * 2;                    // bytes per A row in tile
  constexpr int APF = BM * CPR / 256;           // A issues per thread per step
  constexpr int NB = KSL * NF;                  // B frag loads per lane per step

  __shared__ unsigned short As[2][BM * BK];
  __shared__ int IdxS[27 * BM];

  const int tid = threadIdx.x;
  const int lane = tid & 63;
  const int wave = tid >> 6;
  const int wm = wave / WN;
  const int wn = wave % WN;
  const int base = blockIdx.x * BM;
  const int q = lane >> 4;
  const int l16 = lane & 15;

  // ---- stage all 27*BM neighbor indices once ----
  for (int f = tid; f < 27 * BM; f += 256) {
    int nn = base + (f & (BM - 1));
    IdxS[f] = (nn < nr) ? nbr[(size_t)(f >> 7) * nr + nn] : nr;
  }
  __syncthreads();  // clean vmcnt baseline before the pipeline

  // per-lane B base
  const unsigned short* bbase = Bp + ((size_t)q * COUT + wn * WCOLS + l16) * 8;

  bf16x8 bA[NB], bB[NB];

  auto loadB = [&](bf16x8(&dst)[NB], int s) {
    const int k = s / H;
    const int hh = s % H;
#pragma unroll
    for (int ks = 0; ks < KSL; ++ks)
#pragma unroll
      for (int j = 0; j < NF; ++j) {
        const int ksg = hh * KSL + ks;
        dst[ks * NF + j] = *(const bf16x8*)(
            bbase + ((size_t)k * CIN * COUT) + ((size_t)(ksg * 4) * COUT + j * 16) * 8);
      }
  };

  auto issueA = [&](int s) {
    const int k = s / H;
    const int hh = s % H;
    const int kb = s & 1;
#pragma unroll
    for (int pp = 0; pp < APF; ++pp) {
      int slot = pp * 256 + tid;
      int r = slot / CPR;
      int cc = (slot % CPR) * 16;
      int csw = cc ^ ((r & SWZ) << 4);  // pre-swizzled source chunk (within step row)
      int g = IdxS[k * BM + r];
      gload16(X + (size_t)g * CIN + hh * BK + (csw >> 1),
              (char*)(&As[kb][0]) + slot * 16);
    }
  };

  f32x4 acc[MF][NF] = {};

  auto mfmaStep = [&](int kb, const bf16x8(&bf)[NB]) {
    const char* Ab = (const char*)(&As[kb][0]);
#pragma unroll
    for (int ks = 0; ks < KSL; ++ks) {
      bf16x8 af[MF];
#pragma unroll
      for (int i = 0; i < MF; ++i) {
        int r = wm * WROWS + i * 16 + l16;
        int db = r * RB + (((ks * 64 + q * 16) & (RB - 1)) ^ ((r & SWZ) << 4));
        af[i] = __builtin_bit_cast(bf16x8, *(const uint4*)(Ab + db));
      }
#pragma unroll
      for (int i = 0; i < MF; ++i)
#pragma unroll
        for (int j = 0; j < NF; ++j)
          acc[i][j] = __builtin_amdgcn_mfma_f32_16x16x32_bf16(af[i], bf[ks * NF + j],
                                                              acc[i][j], 0, 0, 0);
    }
  };

  loadB(bA, 0);
  issueA(0);

#pragma unroll 1
  for (int s = 0; s + 1 < S; s += 2) {
    // ---- even half: compute s from bA/As[0], prefetch s+1 ----
    loadB(bB, s + 1);
    issueA(s + 1);
    waitvm<NB + APF>();  // A(s)+B(s) landed; s+1 stays in flight
    BARRIER();
    mfmaStep(0, bA);
    BARRIER();
    // ---- odd half: compute s+1 from bB/As[1], prefetch s+2 ----
    if (s + 2 < S) {
      loadB(bA, s + 2);
      issueA(s + 2);
      waitvm<NB + APF>();
    } else {
      waitvm<0>();
    }
    BARRIER();
    mfmaStep(1, bB);
    BARRIER();
  }
  if constexpr (S & 1) {
    // ---- tail (odd S): last step sits in bA/As[0] ----
    waitvm<0>();
    BARRIER();
    mfmaStep(0, bA);
  }

  // ---- epilogue: C layout col=lane&15, row=(lane>>4)*4+reg ----
#pragma unroll
  for (int i = 0; i < MF; ++i)
#pragma unroll
    for (int j = 0; j < NF; ++j)
#pragma unroll
      for (int r = 0; r < 4; ++r) {
        int row = base + wm * WROWS + i * 16 + q * 4 + r;
        int col = wn * WCOLS + j * 16 + l16;
        if (row < nr) {
          float v = acc[i][j][r];
          if constexpr (FINAL)
            OUT[(size_t)row * COUT + col] = v + DS[(size_t)row * COUT + col];
          else
            Y[(size_t)row * COUT + col] = f2bf(v);
        }
      }
}

// ---------------- launch ----------------
extern "C" void kernel_launch(void* const* d_in, const int* in_sizes, int n_in,
                              void* d_out, int out_size, void* d_ws, size_t ws_size,
                              hipStream_t stream) {
  const float* feats = (const float*)d_in[0];
  const float* W0 = (const float*)d_in[1];
  const float* W1 = (const float*)d_in[2];
  const float* W2 = (const float*)d_in[3];
  const int* nbr = (const int*)d_in[4];
  const int n = in_sizes[0] / 128;
  float* out = (float*)d_out;

  char* p = (char*)d_ws;
  auto take = [&](size_t bytes) {
    char* r = p;
    p += (bytes + 255) & ~(size_t)255;
    return r;
  };
  unsigned short* resB = (unsigned short*)take((size_t)(n + 1) * 128 * 2);
  unsigned short* y0 = (unsigned short*)take((size_t)(n + 1) * 128 * 2);
  unsigned short* y1 = (unsigned short*)take((size_t)(n + 1) * 32 * 2);
  float* ds = (float*)take((size_t)n * 32 * 4);
  unsigned short* p0 = (unsigned short*)take((size_t)27 * 128 * 128 * 2);
  unsigned short* p1 = (unsigned short*)take((size_t)27 * 128 * 32 * 2);
  unsigned short* p2 = (unsigned short*)take((size_t)27 * 32 * 32 * 2);

  prep_kernel<<<(n + 15) / 16, 256, 0, stream>>>(feats, resB, ds, n);
  pack_kernel<<<284, 256, 0, stream>>>(W0, W1, W2, p0, p1, p2);
  zero_tail<<<1, 128, 0, stream>>>(resB + (size_t)n * 128, y0 + (size_t)n * 128,
                                   y1 + (size_t)n * 32);
  const int gb = (n + 127) / 128;
  // conv0: 128->128. WM=1,WN=4 (proven); BK=64 -> LDS 46.6KB -> 3 blocks/CU.
  spconv<128, 128, 64, 1, 4, false, 3>
      <<<gb, 256, 0, stream>>>(resB, p0, nbr, y0, nullptr, nullptr, n);
  // conv1: 128->32. WM=4,WN=1; BK=64 -> 3 blocks/CU.
  spconv<128, 32, 64, 4, 1, false, 3>
      <<<gb, 256, 0, stream>>>(y0, p1, nbr, y1, nullptr, nullptr, n);
  // conv2: 32->32. BK=CIN=32 (identical behavior to round-0), 4+ blocks/CU.
  spconv<32, 32, 32, 4, 1, true, 4>
      <<<gb, 256, 0, stream>>>(y1, p2, nbr, nullptr, out, ds, n);
}